// Round 1
// 85.146 us; speedup vs baseline: 1.0065x; 1.0065x over previous
//
#include <hip/hip_runtime.h>

#define HH 2048
#define WW 2048
#define RPT 8               // output rows per thread
#define CPT 4               // output cols per thread
#define NCG (WW / CPT)      // 512 column groups
#define NRS (HH / RPT)      // 256 row strips
// total threads = NCG * NRS = 131072 -> 512 blocks of 256

__global__ __launch_bounds__(256, 2)
void UnfoldPlainFit_42477226558039_kernel(const float* __restrict__ x,
                                          float* __restrict__ out) {
    const int g     = blockIdx.x * 256 + threadIdx.x;
    const int cg    = g & (NCG - 1);      // consecutive lanes -> consecutive col groups
    const int strip = g >> 9;             // g / NCG
    const int c0    = cg * CPT;
    const int r0    = strip * RPT;

    // Only the outermost column groups need per-element clamping.
    const bool interior = (cg != 0) && (cg != NCG - 1);

    // 7-row rings of horizontal sums; fully-unrolled shifts become register renames.
    float s[7][CPT]  = {};   // plain 7-tap row sums
    float wv[7][CPT] = {};   // x-weighted 7-tap row sums

#pragma unroll
    for (int i = 0; i < RPT + 6; ++i) {
        int gr = r0 - 3 + i;
        gr = max(0, min(HH - 1, gr));     // replication pad: whole-row clamp
        const float* __restrict__ row = x + (size_t)gr * WW;

        // Row buffer v[0..11] covers cols c0-4 .. c0+7 (we use c0-3 .. c0+6).
        float v[12];
        if (interior) {
            const float4 a = *reinterpret_cast<const float4*>(row + c0 - 4);
            const float4 b = *reinterpret_cast<const float4*>(row + c0);
            const float4 c = *reinterpret_cast<const float4*>(row + c0 + 4);
            v[0] = a.x; v[1] = a.y; v[2]  = a.z; v[3]  = a.w;
            v[4] = b.x; v[5] = b.y; v[6]  = b.z; v[7]  = b.w;
            v[8] = c.x; v[9] = c.y; v[10] = c.z; v[11] = c.w;
        } else {
#pragma unroll
            for (int j = 0; j < 12; ++j) {
                int gc = c0 - 4 + j;
                gc = max(0, min(WW - 1, gc));   // replication pad: col clamp
                v[j] = row[gc];
            }
        }

        // Shift rings down (free under full unroll).
#pragma unroll
        for (int k = 0; k < 6; ++k)
#pragma unroll
            for (int cc = 0; cc < CPT; ++cc) {
                s[k][cc]  = s[k + 1][cc];
                wv[k][cc] = wv[k + 1][cc];
            }

        // Horizontal 7-tap sums for the newest row; first col direct, rest sliding.
        // col c0 -> window v[1..7]
        float hs = v[1] + v[2] + v[3] + v[4] + v[5] + v[6] + v[7];
        float hw = (v[5] - v[3]) + 2.f * (v[6] - v[2]) + 3.f * (v[7] - v[1]);
        s[6][0]  = hs;
        wv[6][0] = hw;
#pragma unroll
        for (int cc = 1; cc < CPT; ++cc) {
            const float vl = v[cc];       // x[(c0+cc-1)-3], element leaving the window
            const float vr = v[cc + 7];   // x[(c0+cc)+3],   element entering
            const float sn = hs - vl + vr;
            const float wn = hw + 4.f * vl + 3.f * vr - hs;
            s[6][cc]  = sn;
            wv[6][cc] = wn;
            hs = sn;
            hw = wn;
        }

        // Once the ring is full, emit one output row (i-6).
        if (i >= 6) {
            const int r = r0 + (i - 6);
            float o[12];
#pragma unroll
            for (int cc = 0; cc < CPT; ++cc) {
                const float C2 = s[0][cc] + s[1][cc] + s[2][cc] + s[3][cc]
                               + s[4][cc] + s[5][cc] + s[6][cc];
                const float C1 = 3.f * (s[6][cc] - s[0][cc])
                               + 2.f * (s[5][cc] - s[1][cc])
                               +       (s[4][cc] - s[2][cc]);
                const float C0 = wv[0][cc] + wv[1][cc] + wv[2][cc] + wv[3][cc]
                               + wv[4][cc] + wv[5][cc] + wv[6][cc];
                o[cc * 3 + 0] = C0 * (1.0f / 196.0f);
                o[cc * 3 + 1] = C1 * (1.0f / 196.0f);
                o[cc * 3 + 2] = C2 * (1.0f / 49.0f);
            }
            // 12 contiguous floats per thread; (r*WW + c0)*3*4 bytes is a multiple
            // of 48 -> 16B-aligned. Wave lanes cover contiguous 3 KB.
            float* __restrict__ op = out + ((size_t)r * WW + c0) * 3;
            *reinterpret_cast<float4*>(op + 0) = make_float4(o[0], o[1], o[2],  o[3]);
            *reinterpret_cast<float4*>(op + 4) = make_float4(o[4], o[5], o[6],  o[7]);
            *reinterpret_cast<float4*>(op + 8) = make_float4(o[8], o[9], o[10], o[11]);
        }
    }
}

extern "C" void kernel_launch(void* const* d_in, const int* in_sizes, int n_in,
                              void* d_out, int out_size, void* d_ws, size_t ws_size,
                              hipStream_t stream) {
    const float* x = (const float*)d_in[0];
    float* out = (float*)d_out;
    const int total_threads = NCG * NRS;       // 131072
    dim3 grid(total_threads / 256);            // 512 blocks
    dim3 block(256);
    UnfoldPlainFit_42477226558039_kernel<<<grid, block, 0, stream>>>(x, out);
}

// Round 2
// 84.938 us; speedup vs baseline: 1.0089x; 1.0024x over previous
//
#include <hip/hip_runtime.h>

#define HH 2048
#define WW 2048
#define RPT 4               // output rows per thread
#define CPT 4               // output cols per thread
#define NCG (WW / CPT)      // 512 column groups
#define NRS (HH / RPT)      // 512 row strips
// total threads = NCG * NRS = 262144 -> 1024 blocks of 256

__global__ __launch_bounds__(256, 4)
void UnfoldPlainFit_42477226558039_kernel(const float* __restrict__ x,
                                          float* __restrict__ out) {
    const int g     = blockIdx.x * 256 + threadIdx.x;
    const int cg    = g & (NCG - 1);      // consecutive lanes -> consecutive col groups
    const int strip = g >> 9;             // g / NCG
    const int c0    = cg * CPT;
    const int r0    = strip * RPT;

    // Only the outermost column groups need per-element clamping.
    const bool interior = (cg != 0) && (cg != NCG - 1);

    // 7-row rings of horizontal sums; fully-unrolled shifts become register renames.
    float s[7][CPT]  = {};   // plain 7-tap row sums
    float wv[7][CPT] = {};   // x-weighted 7-tap row sums

#pragma unroll
    for (int i = 0; i < RPT + 6; ++i) {
        int gr = r0 - 3 + i;
        gr = max(0, min(HH - 1, gr));     // replication pad: whole-row clamp
        const float* __restrict__ row = x + (size_t)gr * WW;

        // Row buffer v[0..11] covers cols c0-4 .. c0+7 (we use c0-3 .. c0+6).
        float v[12];
        if (interior) {
            const float4 a = *reinterpret_cast<const float4*>(row + c0 - 4);
            const float4 b = *reinterpret_cast<const float4*>(row + c0);
            const float4 c = *reinterpret_cast<const float4*>(row + c0 + 4);
            v[0] = a.x; v[1] = a.y; v[2]  = a.z; v[3]  = a.w;
            v[4] = b.x; v[5] = b.y; v[6]  = b.z; v[7]  = b.w;
            v[8] = c.x; v[9] = c.y; v[10] = c.z; v[11] = c.w;
        } else {
#pragma unroll
            for (int j = 0; j < 12; ++j) {
                int gc = c0 - 4 + j;
                gc = max(0, min(WW - 1, gc));   // replication pad: col clamp
                v[j] = row[gc];
            }
        }

        // Shift rings down (free under full unroll).
#pragma unroll
        for (int k = 0; k < 6; ++k)
#pragma unroll
            for (int cc = 0; cc < CPT; ++cc) {
                s[k][cc]  = s[k + 1][cc];
                wv[k][cc] = wv[k + 1][cc];
            }

        // Horizontal 7-tap sums for the newest row; first col direct, rest sliding.
        // col c0 -> window v[1..7]
        float hs = v[1] + v[2] + v[3] + v[4] + v[5] + v[6] + v[7];
        float hw = (v[5] - v[3]) + 2.f * (v[6] - v[2]) + 3.f * (v[7] - v[1]);
        s[6][0]  = hs;
        wv[6][0] = hw;
#pragma unroll
        for (int cc = 1; cc < CPT; ++cc) {
            const float vl = v[cc];       // x[(c0+cc-1)-3], element leaving the window
            const float vr = v[cc + 7];   // x[(c0+cc)+3],   element entering
            const float sn = hs - vl + vr;
            const float wn = hw + 4.f * vl + 3.f * vr - hs;
            s[6][cc]  = sn;
            wv[6][cc] = wn;
            hs = sn;
            hw = wn;
        }

        // Once the ring is full, emit one output row (i-6).
        if (i >= 6) {
            const int r = r0 + (i - 6);
            float4 o0, o1, o2;
            {
                const float C2a = s[0][0]+s[1][0]+s[2][0]+s[3][0]+s[4][0]+s[5][0]+s[6][0];
                const float C1a = 3.f*(s[6][0]-s[0][0]) + 2.f*(s[5][0]-s[1][0]) + (s[4][0]-s[2][0]);
                const float C0a = wv[0][0]+wv[1][0]+wv[2][0]+wv[3][0]+wv[4][0]+wv[5][0]+wv[6][0];
                const float C2b = s[0][1]+s[1][1]+s[2][1]+s[3][1]+s[4][1]+s[5][1]+s[6][1];
                const float C1b = 3.f*(s[6][1]-s[0][1]) + 2.f*(s[5][1]-s[1][1]) + (s[4][1]-s[2][1]);
                const float C0b = wv[0][1]+wv[1][1]+wv[2][1]+wv[3][1]+wv[4][1]+wv[5][1]+wv[6][1];
                const float C2c = s[0][2]+s[1][2]+s[2][2]+s[3][2]+s[4][2]+s[5][2]+s[6][2];
                const float C1c = 3.f*(s[6][2]-s[0][2]) + 2.f*(s[5][2]-s[1][2]) + (s[4][2]-s[2][2]);
                const float C0c = wv[0][2]+wv[1][2]+wv[2][2]+wv[3][2]+wv[4][2]+wv[5][2]+wv[6][2];
                const float C2d = s[0][3]+s[1][3]+s[2][3]+s[3][3]+s[4][3]+s[5][3]+s[6][3];
                const float C1d = 3.f*(s[6][3]-s[0][3]) + 2.f*(s[5][3]-s[1][3]) + (s[4][3]-s[2][3]);
                const float C0d = wv[0][3]+wv[1][3]+wv[2][3]+wv[3][3]+wv[4][3]+wv[5][3]+wv[6][3];
                o0 = make_float4(C0a*(1.0f/196.0f), C1a*(1.0f/196.0f), C2a*(1.0f/49.0f),
                                 C0b*(1.0f/196.0f));
                o1 = make_float4(C1b*(1.0f/196.0f), C2b*(1.0f/49.0f),
                                 C0c*(1.0f/196.0f), C1c*(1.0f/196.0f));
                o2 = make_float4(C2c*(1.0f/49.0f),
                                 C0d*(1.0f/196.0f), C1d*(1.0f/196.0f), C2d*(1.0f/49.0f));
            }
            // 12 contiguous floats per thread; (r*WW + c0)*3*4 bytes is a multiple
            // of 48 -> 16B-aligned. Wave lanes cover contiguous 3 KB.
            float* __restrict__ op = out + ((size_t)r * WW + c0) * 3;
            *reinterpret_cast<float4*>(op + 0) = o0;
            *reinterpret_cast<float4*>(op + 4) = o1;
            *reinterpret_cast<float4*>(op + 8) = o2;
        }
    }
}

extern "C" void kernel_launch(void* const* d_in, const int* in_sizes, int n_in,
                              void* d_out, int out_size, void* d_ws, size_t ws_size,
                              hipStream_t stream) {
    const float* x = (const float*)d_in[0];
    float* out = (float*)d_out;
    const int total_threads = NCG * NRS;       // 262144
    dim3 grid(total_threads / 256);            // 1024 blocks
    dim3 block(256);
    UnfoldPlainFit_42477226558039_kernel<<<grid, block, 0, stream>>>(x, out);
}